// Round 6
// baseline (1553.035 us; speedup 1.0000x reference)
//
#include <hip/hip_runtime.h>
#include <hip/hip_bf16.h>

// GRU-GAN generator, MI355X. Round 15 — 8-wave consolidation (from R14's 12).
// B=512, H=64, S=2048, F=32. 32 blocks x 512 threads (8 waves, 2/SIMD).
// Every wave is a gate wave (dir=w>>2, cb=w&3). No idle/slack roles:
//   leg1 (b2->b1), all waves: x-read, 6 gi MFMA (scale-folded weights),
//        merged-rcp GRU elementwise, packed h write.   [prio 1]
//   leg2 (b1->b2):
//     waves 0-3 (dir=0): read h both dirs (4xb128), 6 gh MFMA (fwd),
//        latent tile lt=cb: 2+2 MFMA, lk/lk2, Xs/X2s writes. [prio 1 — gates b2]
//     waves 4-7 (dir=1): read h bwd (2xb128), 6 gh MFMA (bwd);
//        waves 4,5: out-proj y(T-1) from X2s[HB] (stable buffer), 2 MFMA,
//        sigm, un-drained f32x4 global store.          [prio 0 — slack into b2]
// Rationale: per-SIMD issued work <= R14 (6 vs 8 b128 reads, same MFMA count)
// but 33% fewer barrier participants and homogeneous leg1 -> attacks the
// ~700-900cy/step of barrier-synchronized bubbles the issue model can't
// explain. NOT R12's redundant-compute mistake: zero duplicated math.
// All barriers are lgkm-only (waves 4,5 keep global stores in flight).
// Numerics: identical MFMA order + scale folding as R14 -> absmax unchanged.

#define NBATCH 512
#define NH 64
#define NS 2048
#define NF 32
#define MROW 16
#define LDH 72    // padded LDS row stride (shorts): 144 B

typedef short s16x8 __attribute__((ext_vector_type(8)));
typedef float f32x4 __attribute__((ext_vector_type(4)));

#define MFMA(a, b, c) __builtin_amdgcn_mfma_f32_16x16x32_bf16((a), (b), (c), 0, 0, 0)

#define NLOG2E  (-1.4426950408889634f)   // -log2(e)
#define N2LOG2E (-2.8853900817779268f)   // -2*log2(e)

__device__ __forceinline__ void bar_lgkm() {
    // LDS-visibility barrier: drain lgkm only, vmcnt left outstanding
    asm volatile("s_waitcnt lgkmcnt(0)\n\ts_barrier" ::: "memory");
}

__device__ __forceinline__ short f2bf(float f) {
    return (short)((__float_as_uint(f) + 0x8000u) >> 16);
}

__device__ __forceinline__ f32x4 v_exp2(f32x4 a) {
    f32x4 r;
#pragma unroll
    for (int i = 0; i < 4; ++i) r[i] = __builtin_amdgcn_exp2f(a[i]);
    return r;
}

__device__ __forceinline__ f32x4 v_rcp(f32x4 a) {
    f32x4 r;
#pragma unroll
    for (int i = 0; i < 4; ++i) r[i] = __builtin_amdgcn_rcpf(a[i]);
    return r;
}

__device__ __forceinline__ f32x4 v_lk(f32x4 a) {
    f32x4 b = a * 0.01f;
    f32x4 r;
#pragma unroll
    for (int i = 0; i < 4; ++i) r[i] = fmaxf(a[i], b[i]);
    return r;
}

// lk(lk(x)) = max(x, 1e-4*x) in one stage
__device__ __forceinline__ f32x4 v_lk2(f32x4 a) {
    f32x4 b = a * 1e-4f;
    f32x4 r;
#pragma unroll
    for (int i = 0; i < 4; ++i) r[i] = fmaxf(a[i], b[i]);
    return r;
}

// sigmoid of pre-scaled input: a = -log2e * z  ->  1/(1+2^a)
__device__ __forceinline__ f32x4 v_sigm_pre(f32x4 a) {
    return v_rcp(v_exp2(a) + 1.0f);
}

__device__ __forceinline__ int2 pk4bf(f32x4 v) {
    union { __hip_bfloat162 b; int i; } lo, hi;
    float2 a; a.x = v[0]; a.y = v[1];
    float2 b; b.x = v[2]; b.y = v[3];
    lo.b = __float22bfloat162_rn(a);
    hi.b = __float22bfloat162_rn(b);
    int2 r; r.x = lo.i; r.y = hi.i;
    return r;
}

__device__ __forceinline__ s16x8 bfragW(const float* __restrict__ W, int ldk,
                                        int row, int kf, int quad, float scale) {
    const float* p = W + (size_t)row * ldk + kf * 32 + quad * 8;
    s16x8 r;
#pragma unroll
    for (int i = 0; i < 8; ++i) r[i] = f2bf(p[i] * scale);
    return r;
}

__device__ __forceinline__ f32x4 bias4s(const float* __restrict__ p, float scale) {
    const float4 v = *(const float4*)p;
    f32x4 r = {v.x * scale, v.y * scale, v.z * scale, v.w * scale};
    return r;
}

__global__ __launch_bounds__(512)
void grugan_kernel(const float* __restrict__ noise,
                   const float* __restrict__ Wihf, const float* __restrict__ Whhf,
                   const float* __restrict__ bihf, const float* __restrict__ bhhf,
                   const float* __restrict__ Wihb, const float* __restrict__ Whhb,
                   const float* __restrict__ bihb, const float* __restrict__ bhhb,
                   const float* __restrict__ Wlat, const float* __restrict__ blat,
                   const float* __restrict__ Wout, const float* __restrict__ bout,
                   float* __restrict__ out)
{
    __shared__ __align__(16) short Xs[2][MROW][LDH];
    __shared__ __align__(16) short X2s[2][MROW][LDH];
    __shared__ __align__(16) short Hs[2][2][MROW][LDH];

    const int tid  = threadIdx.x;
    const int wave = tid >> 6;
    const int lane = tid & 63;
    const int n    = lane & 15;   // batch row within tile
    const int quad = lane >> 4;
    const int row0 = blockIdx.x * MROW;

    const int dir = wave >> 2;    // 0=fwd, 1=bwd
    const int cb  = wave & 3;     // 16-col j-chunk
    const int jq  = cb * 16 + quad * 4;

    // zero x(0); init h(0)
    for (int idx = tid; idx < MROW * LDH; idx += 512) (&Xs[0][0][0])[idx] = 0;
    f32x4 hreg;
    {
        const float4 nz = *(const float4*)&noise[(size_t)(row0 + n) * NH + jq];
        hreg[0] = nz.x; hreg[1] = nz.y; hreg[2] = nz.z; hreg[3] = nz.w;
        *(int2*)&Hs[0][dir][n][jq] = pk4bf(hreg);
    }
    __syncthreads();

    // ---------------- gate weights (all waves), scale-folded ----------------
    const int jrow = cb * 16 + n;
    const float* Wih = dir ? Wihb : Wihf;
    const float* Whh = dir ? Whhb : Whhf;
    const float* bih = dir ? bihb : bihf;
    const float* bhh = dir ? bhhb : bhhf;

    s16x8 wir0 = bfragW(Wih, NH,   0 + jrow, 0, quad, NLOG2E);
    s16x8 wir1 = bfragW(Wih, NH,   0 + jrow, 1, quad, NLOG2E);
    s16x8 wiz0 = bfragW(Wih, NH,  64 + jrow, 0, quad, NLOG2E);
    s16x8 wiz1 = bfragW(Wih, NH,  64 + jrow, 1, quad, NLOG2E);
    s16x8 win0 = bfragW(Wih, NH, 128 + jrow, 0, quad, N2LOG2E);
    s16x8 win1 = bfragW(Wih, NH, 128 + jrow, 1, quad, N2LOG2E);
    s16x8 whr0 = bfragW(Whh, NH,   0 + jrow, 0, quad, NLOG2E);
    s16x8 whr1 = bfragW(Whh, NH,   0 + jrow, 1, quad, NLOG2E);
    s16x8 whz0 = bfragW(Whh, NH,  64 + jrow, 0, quad, NLOG2E);
    s16x8 whz1 = bfragW(Whh, NH,  64 + jrow, 1, quad, NLOG2E);
    s16x8 whn0 = bfragW(Whh, NH, 128 + jrow, 0, quad, N2LOG2E);
    s16x8 whn1 = bfragW(Whh, NH, 128 + jrow, 1, quad, N2LOG2E);
    f32x4 initR, initZ;
    {
        f32x4 a = bias4s(&bih[jq], NLOG2E), b = bias4s(&bhh[jq], NLOG2E);
        initR = a + b;
        f32x4 c = bias4s(&bih[64 + jq], NLOG2E), d = bias4s(&bhh[64 + jq], NLOG2E);
        initZ = c + d;
    }
    const f32x4 initN1 = bias4s(&bih[128 + jq], N2LOG2E);
    const f32x4 initN2 = bias4s(&bhh[128 + jq], N2LOG2E);

    // ---------------- latent weights (waves 0-3: lt = cb) ----------------
    s16x8 wl0 = {}, wl1 = {}, wl2 = {}, wl3 = {};
    f32x4 initL = {0.f, 0.f, 0.f, 0.f};
    int nq = 0;
    if (dir == 0) {
        const int lt = cb;
        nq  = lt * 16 + quad * 4;
        wl0 = bfragW(Wlat, 2 * NH, lt * 16 + n, 0, quad, 1.0f);
        wl1 = bfragW(Wlat, 2 * NH, lt * 16 + n, 1, quad, 1.0f);
        wl2 = bfragW(Wlat, 2 * NH, lt * 16 + n, 2, quad, 1.0f);
        wl3 = bfragW(Wlat, 2 * NH, lt * 16 + n, 3, quad, 1.0f);
        initL = bias4s(&blat[lt * 16 + quad * 4], 1.0f);
    }

    // ---------------- out-proj (waves 4,5: f0 = cb*16), pre-scaled ----------
    s16x8 wo0 = {}, wo1 = {};
    f32x4 initO = {0.f, 0.f, 0.f, 0.f};
    float* orow = nullptr;
    const bool outw = (wave == 4) || (wave == 5);
    if (outw) {
        const int f0 = cb * 16;
        wo0   = bfragW(Wout, NH, f0 + n, 0, quad, NLOG2E);
        wo1   = bfragW(Wout, NH, f0 + n, 1, quad, NLOG2E);
        initO = bias4s(&bout[f0 + quad * 4], NLOG2E);
        orow  = out + (size_t)(row0 + n) * (NS * NF) + f0 + quad * 4;
    }
    const f32x4 zero4 = {0.f, 0.f, 0.f, 0.f};

    // prologue: gh accumulators for t=0 from h(0)
    f32x4 accR, accZ, accN2;
    {
        s16x8 ha0 = *(const s16x8*)&Hs[0][dir][n][quad * 8];
        s16x8 ha1 = *(const s16x8*)&Hs[0][dir][n][32 + quad * 8];
        accR  = MFMA(whr0, ha0, initR);  accR  = MFMA(whr1, ha1, accR);
        accZ  = MFMA(whz0, ha0, initZ);  accZ  = MFMA(whz1, ha1, accZ);
        accN2 = MFMA(whn0, ha0, initN2); accN2 = MFMA(whn1, ha1, accN2);
    }

#define STEP(HB, T) do {                                                        \
        /* ---- leg1: gate chain (all waves) ---- */                            \
        __builtin_amdgcn_s_setprio(1);                                          \
        s16x8 xa0 = *(const s16x8*)&Xs[HB][n][quad * 8];                        \
        s16x8 xa1 = *(const s16x8*)&Xs[HB][n][32 + quad * 8];                   \
        accR = MFMA(wir0, xa0, accR);   accR = MFMA(wir1, xa1, accR);           \
        accZ = MFMA(wiz0, xa0, accZ);   accZ = MFMA(wiz1, xa1, accZ);           \
        f32x4 accN1 = MFMA(win0, xa0, initN1);                                  \
        accN1 = MFMA(win1, xa1, accN1);                                         \
        f32x4 eR = v_exp2(accR);                                                \
        f32x4 rr = v_rcp(eR + 1.0f);                                            \
        f32x4 eU = v_exp2(accN1 + rr * accN2);                                  \
        f32x4 eZ = v_exp2(accZ);                                                \
        f32x4 numer = (eZ + hreg) + eU * (hreg - eZ);                           \
        f32x4 denom = (eU + 1.0f) * (eZ + 1.0f);                                \
        hreg = numer * v_rcp(denom);                                            \
        *(int2*)&Hs[(HB) ^ 1][dir][n][jq] = pk4bf(hreg);                        \
        __builtin_amdgcn_s_setprio(0);                                          \
        bar_lgkm();  /* b1: H(T+1) visible */                                   \
        /* ---- leg2 ---- */                                                    \
        if (dir == 0) {                                                         \
            /* latent-owner: both-dir h read, gh (fwd), latent tile, writes */  \
            __builtin_amdgcn_s_setprio(1);                                      \
            s16x8 fa0 = *(const s16x8*)&Hs[(HB) ^ 1][0][n][quad * 8];           \
            s16x8 fa1 = *(const s16x8*)&Hs[(HB) ^ 1][0][n][32 + quad * 8];      \
            s16x8 ba0 = *(const s16x8*)&Hs[(HB) ^ 1][1][n][quad * 8];           \
            s16x8 ba1 = *(const s16x8*)&Hs[(HB) ^ 1][1][n][32 + quad * 8];      \
            f32x4 lac1 = MFMA(wl0, fa0, initL);                                 \
            lac1 = MFMA(wl1, fa1, lac1);                                        \
            f32x4 lac2 = MFMA(wl2, ba0, zero4);                                 \
            lac2 = MFMA(wl3, ba1, lac2);                                        \
            f32x4 la = lac1 + lac2;                                             \
            *(int2*)&Xs[(HB) ^ 1][n][nq]  = pk4bf(v_lk(la));                    \
            *(int2*)&X2s[(HB) ^ 1][n][nq] = pk4bf(v_lk2(la));                   \
            accR  = MFMA(whr0, fa0, initR);  accR  = MFMA(whr1, fa1, accR);     \
            accZ  = MFMA(whz0, fa0, initZ);  accZ  = MFMA(whz1, fa1, accZ);     \
            accN2 = MFMA(whn0, fa0, initN2); accN2 = MFMA(whn1, fa1, accN2);    \
            __builtin_amdgcn_s_setprio(0);                                      \
        } else {                                                                \
            /* bwd gh; waves 4,5: out-proj of y(T-1) from stable X2s[HB] */     \
            s16x8 ba0 = *(const s16x8*)&Hs[(HB) ^ 1][1][n][quad * 8];           \
            s16x8 ba1 = *(const s16x8*)&Hs[(HB) ^ 1][1][n][32 + quad * 8];      \
            accR  = MFMA(whr0, ba0, initR);  accR  = MFMA(whr1, ba1, accR);     \
            accZ  = MFMA(whz0, ba0, initZ);  accZ  = MFMA(whz1, ba1, accZ);     \
            accN2 = MFMA(whn0, ba0, initN2); accN2 = MFMA(whn1, ba1, accN2);    \
            if (outw && (T) > 0) {                                              \
                s16x8 p0 = *(const s16x8*)&X2s[HB][n][quad * 8];                \
                s16x8 p1 = *(const s16x8*)&X2s[HB][n][32 + quad * 8];           \
                f32x4 po = MFMA(wo0, p0, initO);                                \
                po = MFMA(wo1, p1, po);                                         \
                *(f32x4*)(orow + (size_t)((T) - 1) * NF) = v_sigm_pre(po);      \
            }                                                                   \
        }                                                                       \
        bar_lgkm();  /* b2: x(T+1) visible */                                   \
    } while (0)

    for (int t = 0; t < NS; t += 2) {
        STEP(0, t);
        STEP(1, t + 1);
    }
#undef STEP

    // epilogue: y(NS-1) from X2s[0] (= lk2(x(NS)), visible via final b2)
    if (outw) {
        s16x8 p0 = *(const s16x8*)&X2s[0][n][quad * 8];
        s16x8 p1 = *(const s16x8*)&X2s[0][n][32 + quad * 8];
        f32x4 po = MFMA(wo0, p0, initO);
        po = MFMA(wo1, p1, po);
        *(f32x4*)(orow + (size_t)(NS - 1) * NF) = v_sigm_pre(po);
    }
}

extern "C" void kernel_launch(void* const* d_in, const int* in_sizes, int n_in,
                              void* d_out, int out_size, void* d_ws, size_t ws_size,
                              hipStream_t stream) {
    const float* noise = (const float*)d_in[0];
    const float* Wihf  = (const float*)d_in[1];
    const float* Whhf  = (const float*)d_in[2];
    const float* bihf  = (const float*)d_in[3];
    const float* bhhf  = (const float*)d_in[4];
    const float* Wihb  = (const float*)d_in[5];
    const float* Whhb  = (const float*)d_in[6];
    const float* bihb  = (const float*)d_in[7];
    const float* bhhb  = (const float*)d_in[8];
    const float* Wlat  = (const float*)d_in[9];
    const float* blat  = (const float*)d_in[10];
    const float* Wout  = (const float*)d_in[11];
    const float* bout  = (const float*)d_in[12];

    grugan_kernel<<<dim3(NBATCH / MROW), dim3(512), 0, stream>>>(
        noise, Wihf, Whhf, bihf, bhhf, Wihb, Whhb, bihb, bhhb,
        Wlat, blat, Wout, bout, (float*)d_out);
}